// Round 14
// baseline (210.831 us; speedup 1.0000x reference)
//
#include <hip/hip_runtime.h>
#include <hip/hip_fp16.h>

#define B_SZ 4096
#define T_SZ 200
#define IN_SZ 34
#define GSEQ 8                      // sequences per workgroup
#define NWG (B_SZ / GSEQ)           // 512 workgroups
#define ROWS (GSEQ * T_SZ)          // 1600 rows per workgroup
#define LDS_T_STRIDE 36             // uint2 per t (32 used + 4 pad: bank-clean)
// HIDDEN = 4, 4*H = 16 gates, gate order i,f,g,o (rows of W_ih/W_hh)
//
// Fully fused: each workgroup (256 thr) owns 8 sequences.
//  Phase A: 16 lanes per row. Lane (q=lane16>>2, r=lane16&3) computes gates
//    {q,4+q,8+q,12+q} over k quarter r (8 k + 2 tail on r==0): weight
//    footprint 40 VGPRs (R13's 144 spilled -> 208us). quad_red over r;
//    r==0 lanes write fp16 gates to LDS [t][s*4+q], stride 36 (bank-clean).
//  Phase B: scan from LDS, 2 seqs per wave, R13-proven numerics.

__device__ __forceinline__ float sigf(float x) {
    return 1.0f / (1.0f + __expf(-x));
}
__device__ __forceinline__ float tanh_f(float x) {
    return 2.0f / (1.0f + __expf(-2.0f * x)) - 1.0f;
}

// quad broadcasts (lane L of each 4-lane group to all 4)
__device__ __forceinline__ float quad_bcast0(float v) {
    int s = __float_as_int(v);
    return __int_as_float(__builtin_amdgcn_update_dpp(s, s, 0x00, 0xf, 0xf, true));
}
__device__ __forceinline__ float quad_bcast1(float v) {
    int s = __float_as_int(v);
    return __int_as_float(__builtin_amdgcn_update_dpp(s, s, 0x55, 0xf, 0xf, true));
}
__device__ __forceinline__ float quad_bcast2(float v) {
    int s = __float_as_int(v);
    return __int_as_float(__builtin_amdgcn_update_dpp(s, s, 0xAA, 0xf, 0xf, true));
}
__device__ __forceinline__ float quad_bcast3(float v) {
    int s = __float_as_int(v);
    return __int_as_float(__builtin_amdgcn_update_dpp(s, s, 0xFF, 0xf, 0xf, true));
}
// quad butterfly all-reduce (sum over the 4 lanes of each quad) [R13-verified]
__device__ __forceinline__ float quad_red(float v) {
    int s = __float_as_int(v);
    v += __int_as_float(__builtin_amdgcn_update_dpp(s, s, 0xB1, 0xf, 0xf, true)); // [1,0,3,2]
    s = __float_as_int(v);
    v += __int_as_float(__builtin_amdgcn_update_dpp(s, s, 0x4E, 0xf, 0xf, true)); // [2,3,0,1]
    return v;
}

__global__ __launch_bounds__(256, 2) void lstm_all(
    const float* __restrict__ x, const float* __restrict__ W_ih,
    const float* __restrict__ W_hh, const float* __restrict__ b_ih,
    const float* __restrict__ b_hh, const float* __restrict__ W_fc,
    const float* __restrict__ b_fc, float* __restrict__ out) {
  __shared__ uint2 gl[T_SZ * LDS_T_STRIDE];  // 57,600 B
  const int tid = threadIdx.x;
  const int lane = tid & 63;
  const int w = tid >> 6;            // wave 0..3
  const int lane16 = lane & 15;
  const int rowgrp = lane >> 4;      // 0..3: row within the wave's 4-row pack
  const int q = lane16 >> 2;         // gate column / hidden unit 0..3
  const int r = lane16 & 3;          // k quarter 0..3
  const int wg = blockIdx.x;

  // ---- per-lane weights: 4 gates x (8 k + 2 tail) = 40 VGPRs ----
  float wv[4][10];
  #pragma unroll
  for (int z = 0; z < 4; ++z) {
    #pragma unroll
    for (int kk = 0; kk < 8; ++kk)
      wv[z][kk] = W_ih[(z * 4 + q) * IN_SZ + r * 8 + kk];
    wv[z][8] = (r == 0) ? W_ih[(z * 4 + q) * IN_SZ + 32] : 0.f;
    wv[z][9] = (r == 0) ? W_ih[(z * 4 + q) * IN_SZ + 33] : 0.f;
  }
  float bias[4];
  #pragma unroll
  for (int z = 0; z < 4; ++z) bias[z] = b_ih[z * 4 + q] + b_hh[z * 4 + q];

  // ---- Phase A: gates for this wg's 1600 rows -> LDS ----
  const char* xb = reinterpret_cast<const char*>(x) + (size_t)wg * ROWS * 136;
  #pragma unroll 1
  for (int i = 0; i < ROWS / 16; ++i) {        // 100 iters, 4 rows/wave/iter
    int ri = i * 16 + w * 4 + rowgrp;          // 0..1599
    const char* rp = xb + (size_t)ri * 136;
    float xv[10];
    #pragma unroll
    for (int m = 0; m < 4; ++m) {              // 8B-aligned float2 loads
      float2 v = *reinterpret_cast<const float2*>(rp + r * 32 + m * 8);
      xv[2 * m] = v.x;
      xv[2 * m + 1] = v.y;
    }
    if (r == 0) {
      float2 vt = *reinterpret_cast<const float2*>(rp + 128);
      xv[8] = vt.x;
      xv[9] = vt.y;
    } else {
      xv[8] = 0.f;
      xv[9] = 0.f;
    }
    float acc[4];
    #pragma unroll
    for (int z = 0; z < 4; ++z) {
      float a = 0.f;
      #pragma unroll
      for (int kk = 0; kk < 10; ++kk) a = fmaf(xv[kk], wv[z][kk], a);
      acc[z] = quad_red(a);                    // sum over k quarters
    }
    if (r == 0) {                              // one writer per (row, q)
      unsigned s = (unsigned)ri / 200u;
      unsigned t = (unsigned)ri - s * 200u;
      union { __half2 h[2]; uint2 v; } u;
      u.h[0] = __floats2half2_rn(acc[0] + bias[0], acc[1] + bias[1]);  // i,f
      u.h[1] = __floats2half2_rn(acc[2] + bias[2], acc[3] + bias[3]);  // g,o
      gl[t * LDS_T_STRIDE + s * 4 + q] = u.v;
    }
  }
  __syncthreads();

  // ---- Phase B: scan. wave w handles seqs 2w, 2w+1 on lanes 0..7 ----
  if (lane < 8) {
    const int s = 2 * w + (lane >> 2);
    const int jq = lane & 3;
    float Wi[4], Wf[4], Wg[4], Wo[4];
    #pragma unroll
    for (int k = 0; k < 4; ++k) {
      Wi[k] = W_hh[(0 + jq) * 4 + k];
      Wf[k] = W_hh[(4 + jq) * 4 + k];
      Wg[k] = W_hh[(8 + jq) * 4 + k];
      Wo[k] = W_hh[(12 + jq) * 4 + k];
    }
    float h[4] = {0.f, 0.f, 0.f, 0.f};
    float c = 0.f;

    auto step = [&](uint2 wv_) {
      union { uint2 u; __half2 h2[2]; } v;
      v.u = wv_;
      float2 p01 = __half22float2(v.h2[0]);  // (i, f)
      float2 p23 = __half22float2(v.h2[1]);  // (g, o)
      float pi = p01.x, pf = p01.y, pg = p23.x, po = p23.y;
      #pragma unroll
      for (int k = 0; k < 4; ++k) {
        pi = fmaf(Wi[k], h[k], pi);
        pf = fmaf(Wf[k], h[k], pf);
        pg = fmaf(Wg[k], h[k], pg);
        po = fmaf(Wo[k], h[k], po);
      }
      float iv = sigf(pi);
      float fv = sigf(pf);
      float gv = tanh_f(pg);
      float ov = sigf(po);
      c = fmaf(fv, c, iv * gv);
      float hj = ov * tanh_f(c);
      h[0] = quad_bcast0(hj);
      h[1] = quad_bcast1(hj);
      h[2] = quad_bcast2(hj);
      h[3] = quad_bcast3(hj);
    };

    const uint2* lp = &gl[s * 4 + jq];
    #pragma unroll 1
    for (int tb = 0; tb < 20; ++tb) {
      uint2 v[10];
      #pragma unroll
      for (int u = 0; u < 10; ++u)
        v[u] = lp[(size_t)(tb * 10 + u) * LDS_T_STRIDE];  // batched ds_reads
      #pragma unroll
      for (int u = 0; u < 10; ++u) step(v[u]);
    }

    if (jq < 3) {
      float a = b_fc[jq];
      #pragma unroll
      for (int k = 0; k < 4; ++k) a = fmaf(W_fc[jq * 4 + k], h[k], a);
      out[(wg * GSEQ + s) * 3 + jq] = a;
    }
  }
}

extern "C" void kernel_launch(void* const* d_in, const int* in_sizes, int n_in,
                              void* d_out, int out_size, void* d_ws, size_t ws_size,
                              hipStream_t stream) {
  const float* x    = (const float*)d_in[0];
  const float* W_ih = (const float*)d_in[1];
  const float* W_hh = (const float*)d_in[2];
  const float* b_ih = (const float*)d_in[3];
  const float* b_hh = (const float*)d_in[4];
  const float* W_fc = (const float*)d_in[5];
  const float* b_fc = (const float*)d_in[6];
  float* out = (float*)d_out;
  (void)in_sizes; (void)n_in; (void)out_size; (void)d_ws; (void)ws_size;

  hipLaunchKernelGGL(lstm_all, dim3(NWG), dim3(256), 0, stream,
                     x, W_ih, W_hh, b_ih, b_hh, W_fc, b_fc, out);
}

// Round 15
// 89.688 us; speedup vs baseline: 2.3507x; 2.3507x over previous
//
#include <hip/hip_runtime.h>

#define B_SZ 4096
#define T_SZ 200
#define IN_SZ 34
// HIDDEN = 4, 4*H = 16 gates, gate order i,f,g,o (rows of W_ih/W_hh)
// xg layout: [row = b*T+t][j=0..3][gate i,f,g,o] fp32 — 64B/row, contiguous
// float4 stores (R1-measured 43us producer), float4 loads (R2-measured 10.6us
// consumer).

__device__ __forceinline__ float sigf(float x) {
    return 1.0f / (1.0f + __expf(-x));
}
__device__ __forceinline__ float tanh_f(float x) {
    return 2.0f / (1.0f + __expf(-2.0f * x)) - 1.0f;
}

// broadcast lane L (0..3) of each quad to all 4 lanes of the quad via DPP
__device__ __forceinline__ float quad_bcast0(float v) {
    int s = __float_as_int(v);
    return __int_as_float(__builtin_amdgcn_update_dpp(s, s, 0x00, 0xf, 0xf, true));
}
__device__ __forceinline__ float quad_bcast1(float v) {
    int s = __float_as_int(v);
    return __int_as_float(__builtin_amdgcn_update_dpp(s, s, 0x55, 0xf, 0xf, true));
}
__device__ __forceinline__ float quad_bcast2(float v) {
    int s = __float_as_int(v);
    return __int_as_float(__builtin_amdgcn_update_dpp(s, s, 0xAA, 0xf, 0xf, true));
}
__device__ __forceinline__ float quad_bcast3(float v) {
    int s = __float_as_int(v);
    return __int_as_float(__builtin_amdgcn_update_dpp(s, s, 0xFF, 0xf, 0xf, true));
}

// Phase 1 (R1-exact): x_gates[row][j][gt] = dot(x[row], W_ih[gt*4+j]) + biases
__global__ __launch_bounds__(256) void xgates_kernel(
    const float* __restrict__ x, const float* __restrict__ W_ih,
    const float* __restrict__ b_ih, const float* __restrict__ b_hh,
    float* __restrict__ xg) {
  int row = blockIdx.x * 256 + threadIdx.x;  // exactly B*T threads launched
  float xr[IN_SZ];
  const float2* xp = reinterpret_cast<const float2*>(x + (size_t)row * IN_SZ);
  #pragma unroll
  for (int k = 0; k < IN_SZ / 2; ++k) {
    float2 v = xp[k];
    xr[2 * k] = v.x;
    xr[2 * k + 1] = v.y;
  }
  float acc[16];
  #pragma unroll
  for (int g = 0; g < 16; ++g) acc[g] = b_ih[g] + b_hh[g];  // uniform s_loads
  #pragma unroll
  for (int k = 0; k < IN_SZ; ++k) {
    #pragma unroll
    for (int g = 0; g < 16; ++g)
      acc[g] = fmaf(xr[k], W_ih[g * IN_SZ + k], acc[g]);  // W uniform -> SGPR
  }
  // write [row][j=0..3][gt=i,f,g,o] as 4 float4s (64B contiguous)
  float4* op = reinterpret_cast<float4*>(xg + (size_t)row * 16);
  #pragma unroll
  for (int j = 0; j < 4; ++j)
    op[j] = make_float4(acc[j], acc[4 + j], acc[8 + j], acc[12 + j]);
}

// Phase 2 (R2-exact): 4 lanes per batch element, lane j owns h_j/c_j.
// Register double-buffered prefetch (U=10), DPP quad broadcasts for h.
#define U_SZ 10
__global__ __launch_bounds__(64) void lstm_scan(
    const float* __restrict__ xg, const float* __restrict__ W_hh,
    const float* __restrict__ W_fc, const float* __restrict__ b_fc,
    float* __restrict__ out) {
  int tid = blockIdx.x * 64 + threadIdx.x;
  int b = tid >> 2;
  int j = tid & 3;
  float Wi[4], Wf[4], Wg[4], Wo[4];
  #pragma unroll
  for (int k = 0; k < 4; ++k) {
    Wi[k] = W_hh[(0 + j) * 4 + k];
    Wf[k] = W_hh[(4 + j) * 4 + k];
    Wg[k] = W_hh[(8 + j) * 4 + k];
    Wo[k] = W_hh[(12 + j) * 4 + k];
  }
  float h[4] = {0.f, 0.f, 0.f, 0.f};
  float c = 0.f;

  auto step = [&](float4 g4) {
    float pi = g4.x, pf = g4.y, pg = g4.z, po = g4.w;
    #pragma unroll
    for (int k = 0; k < 4; ++k) {
      pi = fmaf(Wi[k], h[k], pi);
      pf = fmaf(Wf[k], h[k], pf);
      pg = fmaf(Wg[k], h[k], pg);
      po = fmaf(Wo[k], h[k], po);
    }
    float iv = sigf(pi);
    float fv = sigf(pf);
    float gv = tanh_f(pg);
    float ov = sigf(po);
    c = fmaf(fv, c, iv * gv);
    float hj = ov * tanh_f(c);
    h[0] = quad_bcast0(hj);
    h[1] = quad_bcast1(hj);
    h[2] = quad_bcast2(hj);
    h[3] = quad_bcast3(hj);
  };

  const float4* xp = reinterpret_cast<const float4*>(xg) + (size_t)b * (T_SZ * 4) + j;
  float4 bufA[U_SZ], bufB[U_SZ];
  #pragma unroll
  for (int u = 0; u < U_SZ; ++u) bufA[u] = xp[4 * u];

  // T=200 = 20 blocks of 10; ping-pong pairs
  #pragma unroll 1
  for (int blk = 0; blk < 20; blk += 2) {
    const float4* p1 = xp + (size_t)(blk + 1) * (4 * U_SZ);
    #pragma unroll
    for (int u = 0; u < U_SZ; ++u) bufB[u] = p1[4 * u];
    #pragma unroll
    for (int u = 0; u < U_SZ; ++u) step(bufA[u]);
    if (blk + 2 < 20) {
      const float4* p2 = xp + (size_t)(blk + 2) * (4 * U_SZ);
      #pragma unroll
      for (int u = 0; u < U_SZ; ++u) bufA[u] = p2[4 * u];
    }
    #pragma unroll
    for (int u = 0; u < U_SZ; ++u) step(bufB[u]);
  }

  if (j < 3) {
    float acc = b_fc[j];
    #pragma unroll
    for (int k = 0; k < 4; ++k) acc = fmaf(W_fc[j * 4 + k], h[k], acc);
    out[b * 3 + j] = acc;
  }
}

// Fallback (only if workspace is too small): fused single kernel, W_ih in LDS.
__global__ __launch_bounds__(256) void lstm_fused(
    const float* __restrict__ x, const float* __restrict__ W_ih,
    const float* __restrict__ W_hh, const float* __restrict__ b_ih,
    const float* __restrict__ b_hh, const float* __restrict__ W_fc,
    const float* __restrict__ b_fc, float* __restrict__ out) {
  __shared__ float Ws[16 * IN_SZ];
  for (int i = threadIdx.x; i < 16 * IN_SZ; i += 256) Ws[i] = W_ih[i];
  __syncthreads();
  int tid = blockIdx.x * 256 + threadIdx.x;
  int b = tid >> 2;
  int j = tid & 3;
  float bi = b_ih[0 + j] + b_hh[0 + j];
  float bf = b_ih[4 + j] + b_hh[4 + j];
  float bg = b_ih[8 + j] + b_hh[8 + j];
  float bo = b_ih[12 + j] + b_hh[12 + j];
  float Wi[4], Wf[4], Wg[4], Wo[4];
  #pragma unroll
  for (int k = 0; k < 4; ++k) {
    Wi[k] = W_hh[(0 + j) * 4 + k];
    Wf[k] = W_hh[(4 + j) * 4 + k];
    Wg[k] = W_hh[(8 + j) * 4 + k];
    Wo[k] = W_hh[(12 + j) * 4 + k];
  }
  float h[4] = {0.f, 0.f, 0.f, 0.f};
  float c = 0.f;
  const float2* xp = reinterpret_cast<const float2*>(x + (size_t)b * T_SZ * IN_SZ);
  int lbase = (threadIdx.x & 63) & ~3;
  for (int t = 0; t < T_SZ; ++t) {
    float xr[IN_SZ];
    #pragma unroll
    for (int k = 0; k < IN_SZ / 2; ++k) {
      float2 v = xp[(size_t)t * (IN_SZ / 2) + k];
      xr[2 * k] = v.x;
      xr[2 * k + 1] = v.y;
    }
    float pi = bi, pf = bf, pg = bg, po = bo;
    #pragma unroll
    for (int k = 0; k < IN_SZ; ++k) {
      pi = fmaf(xr[k], Ws[(0 + j) * IN_SZ + k], pi);
      pf = fmaf(xr[k], Ws[(4 + j) * IN_SZ + k], pf);
      pg = fmaf(xr[k], Ws[(8 + j) * IN_SZ + k], pg);
      po = fmaf(xr[k], Ws[(12 + j) * IN_SZ + k], po);
    }
    #pragma unroll
    for (int k = 0; k < 4; ++k) {
      pi = fmaf(Wi[k], h[k], pi);
      pf = fmaf(Wf[k], h[k], pf);
      pg = fmaf(Wg[k], h[k], pg);
      po = fmaf(Wo[k], h[k], po);
    }
    float iv = sigf(pi);
    float fv = sigf(pf);
    float gv = tanh_f(pg);
    float ov = sigf(po);
    c = fmaf(fv, c, iv * gv);
    float hj = ov * tanh_f(c);
    h[0] = __shfl(hj, lbase + 0);
    h[1] = __shfl(hj, lbase + 1);
    h[2] = __shfl(hj, lbase + 2);
    h[3] = __shfl(hj, lbase + 3);
  }
  if (j < 3) {
    float acc = b_fc[j];
    #pragma unroll
    for (int k = 0; k < 4; ++k) acc = fmaf(W_fc[j * 4 + k], h[k], acc);
    out[b * 3 + j] = acc;
  }
}

extern "C" void kernel_launch(void* const* d_in, const int* in_sizes, int n_in,
                              void* d_out, int out_size, void* d_ws, size_t ws_size,
                              hipStream_t stream) {
  const float* x    = (const float*)d_in[0];
  const float* W_ih = (const float*)d_in[1];
  const float* W_hh = (const float*)d_in[2];
  const float* b_ih = (const float*)d_in[3];
  const float* b_hh = (const float*)d_in[4];
  const float* W_fc = (const float*)d_in[5];
  const float* b_fc = (const float*)d_in[6];
  float* out = (float*)d_out;

  const size_t need = (size_t)B_SZ * T_SZ * 16 * sizeof(float);
  if (ws_size >= need) {
    float* xg = (float*)d_ws;
    hipLaunchKernelGGL(xgates_kernel, dim3(B_SZ * T_SZ / 256), dim3(256), 0, stream,
                       x, W_ih, b_ih, b_hh, xg);
    hipLaunchKernelGGL(lstm_scan, dim3(B_SZ * 4 / 64), dim3(64), 0, stream,
                       xg, W_hh, W_fc, b_fc, out);
  } else {
    hipLaunchKernelGGL(lstm_fused, dim3(B_SZ * 4 / 256), dim3(256), 0, stream,
                       x, W_ih, W_hh, b_ih, b_hh, W_fc, b_fc, out);
  }
}